// Round 16
// baseline (181.076 us; speedup 1.0000x reference)
//
#include <hip/hip_runtime.h>

typedef float f32x4 __attribute__((ext_vector_type(4)));
typedef __bf16 bf16x8 __attribute__((ext_vector_type(8)));
typedef _Float16 f16x2 __attribute__((ext_vector_type(2)));
typedef _Float16 f16x8 __attribute__((ext_vector_type(8)));

#define LDT 68

__device__ __forceinline__ unsigned short bf16_bits(float f) {
    return __builtin_bit_cast(unsigned short, (__bf16)f);
}
__device__ __forceinline__ unsigned short f16_bits(float f) {
    return __builtin_bit_cast(unsigned short, (_Float16)f);
}

// Packed Pade[5/4] tanh (R9 exact form), inputs pre-clamped to [-4,4]:
//   tanh x ~ x(945+105x^2+x^4)/(945+420x^2+15x^4), max err 0.0026.
// Reciprocal: packed-u16 magic seed + 2 packed Newton iters. Zero trans ops.
__device__ __forceinline__ unsigned tanh2_pk(float a, float b) {
    f16x2 v = __builtin_bit_cast(f16x2, __builtin_amdgcn_cvt_pkrtz(a, b));
    f16x2 x2 = v * v;
    f16x2 x4 = x2 * x2;
    const f16x2 c945 = {(_Float16)945.f, (_Float16)945.f};
    const f16x2 c105 = {(_Float16)105.f, (_Float16)105.f};
    const f16x2 c420 = {(_Float16)420.f, (_Float16)420.f};
    const f16x2 c15  = {(_Float16)15.f,  (_Float16)15.f};
    const f16x2 one  = {(_Float16)1.f,   (_Float16)1.f};
    f16x2 num = v * (c945 + c105 * x2 + x4);
    f16x2 den = c945 + c420 * x2 + c15 * x4;   // in [945, 13425] > 0
    unsigned r0u = 0x77807780u - __builtin_bit_cast(unsigned, den);
    f16x2 r = __builtin_bit_cast(f16x2, r0u);
    r = r + r * (one - den * r);
    r = r + r * (one - den * r);
    return __builtin_bit_cast(unsigned, num * r);
}
__device__ __forceinline__ float clamp4(float v) {
    return __builtin_amdgcn_fmed3f(v, -4.0f, 4.0f);
}

// ---------------------------------------------------------------------------
// P1 (R9 exact, 256 thr): T = I + 0.02A; M = T^50 via 7 LDS matmuls.
// Writes M (f32) to ws+20480 and W2 f16 fragments to ws[16384..20479].
// ---------------------------------------------------------------------------
__global__ __launch_bounds__(256) void ode_pre1(
        const float* __restrict__ A, const float* __restrict__ W2,
        unsigned short* __restrict__ ws) {
    __shared__ float Ts[64 * LDT];
    __shared__ float Za[64 * LDT];
    __shared__ float ZaT[64 * LDT];
    __shared__ float Zb[64 * LDT];
    __shared__ float ZbT[64 * LDT];
    const int t = threadIdx.x;

    for (int i = t; i < 4096; i += 256) {
        int r = i >> 6, c = i & 63;
        float v = 0.02f * A[i] + ((r == c) ? 1.0f : 0.0f);
        Ts[r * LDT + c] = v;
        Za[r * LDT + c] = v;
        ZaT[c * LDT + r] = v;
    }
    __syncthreads();

    const int r0 = (t >> 4) * 4;
    const int c0 = (t & 15) * 4;
    auto mm = [&](const float* XT, const float* Y, float* Z, float* ZT) {
        float ac[4][4];
        #pragma unroll
        for (int i = 0; i < 4; i++)
            #pragma unroll
            for (int j = 0; j < 4; j++) ac[i][j] = 0.0f;
        #pragma unroll 8
        for (int k = 0; k < 64; k++) {
            float4 a = *(const float4*)(XT + k * LDT + r0);
            float4 b = *(const float4*)(Y + k * LDT + c0);
            ac[0][0] = fmaf(a.x, b.x, ac[0][0]); ac[0][1] = fmaf(a.x, b.y, ac[0][1]);
            ac[0][2] = fmaf(a.x, b.z, ac[0][2]); ac[0][3] = fmaf(a.x, b.w, ac[0][3]);
            ac[1][0] = fmaf(a.y, b.x, ac[1][0]); ac[1][1] = fmaf(a.y, b.y, ac[1][1]);
            ac[1][2] = fmaf(a.y, b.z, ac[1][2]); ac[1][3] = fmaf(a.y, b.w, ac[1][3]);
            ac[2][0] = fmaf(a.z, b.x, ac[2][0]); ac[2][1] = fmaf(a.z, b.y, ac[2][1]);
            ac[2][2] = fmaf(a.z, b.z, ac[2][2]); ac[2][3] = fmaf(a.z, b.w, ac[2][3]);
            ac[3][0] = fmaf(a.w, b.x, ac[3][0]); ac[3][1] = fmaf(a.w, b.y, ac[3][1]);
            ac[3][2] = fmaf(a.w, b.z, ac[3][2]); ac[3][3] = fmaf(a.w, b.w, ac[3][3]);
        }
        #pragma unroll
        for (int i = 0; i < 4; i++)
            *(float4*)(Z + (r0 + i) * LDT + c0) =
                make_float4(ac[i][0], ac[i][1], ac[i][2], ac[i][3]);
        #pragma unroll
        for (int j = 0; j < 4; j++)
            *(float4*)(ZT + (c0 + j) * LDT + r0) =
                make_float4(ac[0][j], ac[1][j], ac[2][j], ac[3][j]);
        __syncthreads();
    };
    // 50 = 0b110010 -> sq, *T, sq, sq, sq, *T, sq  (result in Zb)
    mm(ZaT, Za, Zb, ZbT);  // T^2
    mm(ZbT, Ts, Za, ZaT);  // T^3
    mm(ZaT, Za, Zb, ZbT);  // T^6
    mm(ZbT, Zb, Za, ZaT);  // T^12
    mm(ZaT, Za, Zb, ZbT);  // T^24
    mm(ZbT, Ts, Za, ZaT);  // T^25
    mm(ZaT, Za, Zb, ZbT);  // T^50 -> Zb

    // write M to global for P2
    float* gM = (float*)(ws + 20480);
    for (int i = t; i < 4096; i += 256)
        gM[i] = Zb[(i >> 6) * LDT + (i & 63)];

    // W2 f16 fragments (4096 elems, 16 per thread)
    #pragma unroll
    for (int e = 0; e < 16; e++) {
        int f = t * 16 + e;
        int tt = f >> 9, l = (f >> 3) & 63, j = f & 7;
        int qq = l >> 4, cc = l & 15;
        int n = 16 * (2 * tt + (j >> 2)) + 4 * qq + (j & 3);
        ws[16384 + f] = f16_bits(W2[n * 16 + cc]);
    }
}

// ---------------------------------------------------------------------------
// P2: W1p = M@W1 -> bf16 GEMM1 B-fragments. 64 blocks x 256 threads.
// ---------------------------------------------------------------------------
__global__ __launch_bounds__(256) void ode_pre2(
        const float* __restrict__ W1, unsigned short* __restrict__ ws) {
    const float* M = (const float*)(ws + 20480);
    const int k = blockIdx.x;
    const int col = threadIdx.x;
    const float* mrow = M + k * 64;
    float acc = 0.0f;
    #pragma unroll 8
    for (int d = 0; d < 64; d++)
        acc = fmaf(mrow[d], W1[d * 256 + col], acc);
    const int ntg = col >> 4, cc = col & 15;
    const int kt = k >> 5, qq = (k >> 3) & 3, jj = k & 7;
    ws[((ntg * 2 + kt) * 64 + qq * 16 + cc) * 8 + jj] = bf16_bits(acc);
}

// ---------------------------------------------------------------------------
// Main (R9 + W2-in-registers): out = tanh(x @ W1p + b1) @ W2 + b2.
// One-shot, grid = B/256, 512 thr (8 waves), 32 rows/wave. W2 fragments
// (8 x uint4/lane) preloaded from global at start — latency hidden under w1f
// staging + barrier — so LDS = w1f 32KB + b1s 1KB = 33792 B -> 4 blocks/CU
// (32 waves, was 3/24 at 41984 B). GEMM1 bf16 swapped (h in registers),
// bias via MFMA C-init from LDS, tanh packed-f16 Pade, GEMM2 f16 W2-as-A ->
// transposed C -> coalesced float4 stores. Q-loop unroll 1 (R14: unroll 2
// regressed, register cliff).
// ---------------------------------------------------------------------------
__global__ __launch_bounds__(512, 4) void ode_main(
        const float* __restrict__ x, const unsigned short* __restrict__ wsfrag,
        const float* __restrict__ b1, const float* __restrict__ b2,
        float* __restrict__ out, int B) {
    __shared__ unsigned short w1f[16384];  // bf16 frags, 32KB
    __shared__ float b1s[256];             // 1KB
    const int t = threadIdx.x;
    const int wid = t >> 6, lane = t & 63;
    const int q = lane >> 4, c = lane & 15;
    const long rowbase = (long)blockIdx.x * 256 + wid * 32;

    // ---- issue x loads + W2 fragment loads first (hidden under staging)
    float4 xraw[8];
    #pragma unroll
    for (int s = 0; s < 2; s++) {
        long row = rowbase + 16 * s + c;
        if (row >= B) row = B - 1;
        const float* xp = x + row * 64 + q * 8;
        xraw[s * 4 + 0] = *(const float4*)(xp);
        xraw[s * 4 + 1] = *(const float4*)(xp + 4);
        xraw[s * 4 + 2] = *(const float4*)(xp + 32);
        xraw[s * 4 + 3] = *(const float4*)(xp + 36);
    }
    uint4 w2regs[8];
    {
        const uint4* w2g = (const uint4*)(wsfrag + 16384);  // 512 uint4
        #pragma unroll
        for (int tt = 0; tt < 8; tt++)
            w2regs[tt] = w2g[tt * 64 + lane];
    }

    // ---- stage w1f + bias (33KB)
    {
        const uint4* src = (const uint4*)wsfrag;
        uint4* d1 = (uint4*)w1f;
        #pragma unroll
        for (int i = 0; i < 4; i++) d1[t + 512 * i] = src[t + 512 * i];
        if (t < 64) ((float4*)b1s)[t] = ((const float4*)b1)[t];
    }
    __syncthreads();

    // ---- convert x to bf16 B-fragments, freeing xraw
    bf16x8 xb[2][2];
    #pragma unroll
    for (int s = 0; s < 2; s++)
        #pragma unroll
        for (int kt = 0; kt < 2; kt++) {
            float4 u0 = xraw[s * 4 + kt * 2];
            float4 u1 = xraw[s * 4 + kt * 2 + 1];
            bf16x8 cv;
            cv[0] = (__bf16)u0.x; cv[1] = (__bf16)u0.y;
            cv[2] = (__bf16)u0.z; cv[3] = (__bf16)u0.w;
            cv[4] = (__bf16)u1.x; cv[5] = (__bf16)u1.y;
            cv[6] = (__bf16)u1.z; cv[7] = (__bf16)u1.w;
            xb[s][kt] = cv;
        }

    f32x4 oacc[2] = {{0, 0, 0, 0}, {0, 0, 0, 0}};
    #pragma unroll 1
    for (int Q = 0; Q < 4; Q++) {
        // ---- GEMM1 quarter: 4 ntiles x 2 strips, bias via C-init
        f32x4 acc[2][4];
        #pragma unroll
        for (int m = 0; m < 4; m++) {
            float4 bb = *(const float4*)(b1s + 16 * (4 * Q + m) + 4 * q);
            f32x4 bv = {bb.x, bb.y, bb.z, bb.w};
            acc[0][m] = bv;
            acc[1][m] = bv;
        }
        #pragma unroll
        for (int kt = 0; kt < 2; kt++) {
            #pragma unroll
            for (int m = 0; m < 4; m++) {
                uint4 wraw = *(const uint4*)(w1f + (((4 * Q + m) * 2 + kt) * 64 + lane) * 8);
                bf16x8 wv = __builtin_bit_cast(bf16x8, wraw);
                acc[0][m] = __builtin_amdgcn_mfma_f32_16x16x32_bf16(wv, xb[0][kt], acc[0][m], 0, 0, 0);
                acc[1][m] = __builtin_amdgcn_mfma_f32_16x16x32_bf16(wv, xb[1][kt], acc[1][m], 0, 0, 0);
            }
        }
        // ---- tanh (packed f16) + GEMM2 (2 ttiles), W2 regs as A-operand ->
        //      transposed output for coalesced stores
        #pragma unroll
        for (int p = 0; p < 2; p++) {
            f16x8 w2v = __builtin_bit_cast(f16x8, w2regs[2 * Q + p]);
            #pragma unroll
            for (int s = 0; s < 2; s++) {
                const f32x4 ae = acc[s][2 * p];
                const f32x4 ao = acc[s][2 * p + 1];
                uint4 pr;
                pr.x = tanh2_pk(clamp4(ae[0]), clamp4(ae[1]));
                pr.y = tanh2_pk(clamp4(ae[2]), clamp4(ae[3]));
                pr.z = tanh2_pk(clamp4(ao[0]), clamp4(ao[1]));
                pr.w = tanh2_pk(clamp4(ao[2]), clamp4(ao[3]));
                f16x8 pa = __builtin_bit_cast(f16x8, pr);
                oacc[s] = __builtin_amdgcn_mfma_f32_16x16x32_f16(w2v, pa, oacc[s], 0, 0, 0);
            }
        }
    }
    // ---- store: lane (q,c) holds out[rowbase+16s+c][4q..4q+3] -> float4
    const float4 b2v4 = *(const float4*)(b2 + 4 * q);
    #pragma unroll
    for (int s = 0; s < 2; s++) {
        long row = rowbase + 16 * s + c;
        if (row < B)
            *(float4*)(out + row * 16 + 4 * q) =
                make_float4(oacc[s][0] + b2v4.x, oacc[s][1] + b2v4.y,
                            oacc[s][2] + b2v4.z, oacc[s][3] + b2v4.w);
    }
}

extern "C" void kernel_launch(void* const* d_in, const int* in_sizes, int n_in,
                              void* d_out, int out_size, void* d_ws, size_t ws_size,
                              hipStream_t stream) {
    const float* x  = (const float*)d_in[0];
    const float* A  = (const float*)d_in[1];
    const float* W1 = (const float*)d_in[2];
    const float* b1 = (const float*)d_in[3];
    const float* W2 = (const float*)d_in[4];
    const float* b2 = (const float*)d_in[5];
    float* out = (float*)d_out;
    unsigned short* ws = (unsigned short*)d_ws;  // 40KB frags + 16KB M

    const int B = in_sizes[0] / 64;

    ode_pre1<<<1, 256, 0, stream>>>(A, W2, ws);
    ode_pre2<<<64, 256, 0, stream>>>(W1, ws);
    const int grid = (B + 255) / 256;
    ode_main<<<grid, 512, 0, stream>>>(x, ws, b1, b2, out, B);
}

// Round 17
// 122.169 us; speedup vs baseline: 1.4822x; 1.4822x over previous
//
#include <hip/hip_runtime.h>

typedef float f32x4 __attribute__((ext_vector_type(4)));
typedef __bf16 bf16x8 __attribute__((ext_vector_type(8)));
typedef _Float16 f16x2 __attribute__((ext_vector_type(2)));
typedef _Float16 f16x8 __attribute__((ext_vector_type(8)));

#define LDT 68

__device__ __forceinline__ unsigned short bf16_bits(float f) {
    return __builtin_bit_cast(unsigned short, (__bf16)f);
}
__device__ __forceinline__ unsigned short f16_bits(float f) {
    return __builtin_bit_cast(unsigned short, (_Float16)f);
}

// Packed Pade[5/4] tanh, inputs pre-clamped to [-4,4]:
//   tanh x ~ x(945+105x^2+x^4)/(945+420x^2+15x^4), max err 0.0026.
// Reciprocal: packed-u16 magic seed + ONE packed Newton iter (R17: was 2;
// seed ~6% -> one Newton ~0.4% rel, h abs err <= 0.004 -- within budget).
// Zero trans ops.
__device__ __forceinline__ unsigned tanh2_pk(float a, float b) {
    f16x2 v = __builtin_bit_cast(f16x2, __builtin_amdgcn_cvt_pkrtz(a, b));
    f16x2 x2 = v * v;
    f16x2 x4 = x2 * x2;
    const f16x2 c945 = {(_Float16)945.f, (_Float16)945.f};
    const f16x2 c105 = {(_Float16)105.f, (_Float16)105.f};
    const f16x2 c420 = {(_Float16)420.f, (_Float16)420.f};
    const f16x2 c15  = {(_Float16)15.f,  (_Float16)15.f};
    const f16x2 one  = {(_Float16)1.f,   (_Float16)1.f};
    f16x2 num = v * (c945 + c105 * x2 + x4);
    f16x2 den = c945 + c420 * x2 + c15 * x4;   // in [945, 13425] > 0
    unsigned r0u = 0x77807780u - __builtin_bit_cast(unsigned, den);
    f16x2 r = __builtin_bit_cast(f16x2, r0u);
    r = r + r * (one - den * r);
    return __builtin_bit_cast(unsigned, num * r);
}
__device__ __forceinline__ float clamp4(float v) {
    return __builtin_amdgcn_fmed3f(v, -4.0f, 4.0f);
}

// ---------------------------------------------------------------------------
// P1 (R9 exact): T = I + 0.02A; M = T^50 via 7 LDS matmuls (fp32,
// transposed-copy trick). Writes M (f32) to ws+20480 and W2 f16 fragments
// to ws[16384..20479]. 1 block, 256 threads.
// ---------------------------------------------------------------------------
__global__ __launch_bounds__(256) void ode_pre1(
        const float* __restrict__ A, const float* __restrict__ W2,
        unsigned short* __restrict__ ws) {
    __shared__ float Ts[64 * LDT];
    __shared__ float Za[64 * LDT];
    __shared__ float ZaT[64 * LDT];
    __shared__ float Zb[64 * LDT];
    __shared__ float ZbT[64 * LDT];
    const int t = threadIdx.x;

    for (int i = t; i < 4096; i += 256) {
        int r = i >> 6, c = i & 63;
        float v = 0.02f * A[i] + ((r == c) ? 1.0f : 0.0f);
        Ts[r * LDT + c] = v;
        Za[r * LDT + c] = v;
        ZaT[c * LDT + r] = v;
    }
    __syncthreads();

    const int r0 = (t >> 4) * 4;
    const int c0 = (t & 15) * 4;
    auto mm = [&](const float* XT, const float* Y, float* Z, float* ZT) {
        float ac[4][4];
        #pragma unroll
        for (int i = 0; i < 4; i++)
            #pragma unroll
            for (int j = 0; j < 4; j++) ac[i][j] = 0.0f;
        #pragma unroll 8
        for (int k = 0; k < 64; k++) {
            float4 a = *(const float4*)(XT + k * LDT + r0);
            float4 b = *(const float4*)(Y + k * LDT + c0);
            ac[0][0] = fmaf(a.x, b.x, ac[0][0]); ac[0][1] = fmaf(a.x, b.y, ac[0][1]);
            ac[0][2] = fmaf(a.x, b.z, ac[0][2]); ac[0][3] = fmaf(a.x, b.w, ac[0][3]);
            ac[1][0] = fmaf(a.y, b.x, ac[1][0]); ac[1][1] = fmaf(a.y, b.y, ac[1][1]);
            ac[1][2] = fmaf(a.y, b.z, ac[1][2]); ac[1][3] = fmaf(a.y, b.w, ac[1][3]);
            ac[2][0] = fmaf(a.z, b.x, ac[2][0]); ac[2][1] = fmaf(a.z, b.y, ac[2][1]);
            ac[2][2] = fmaf(a.z, b.z, ac[2][2]); ac[2][3] = fmaf(a.z, b.w, ac[2][3]);
            ac[3][0] = fmaf(a.w, b.x, ac[3][0]); ac[3][1] = fmaf(a.w, b.y, ac[3][1]);
            ac[3][2] = fmaf(a.w, b.z, ac[3][2]); ac[3][3] = fmaf(a.w, b.w, ac[3][3]);
        }
        #pragma unroll
        for (int i = 0; i < 4; i++)
            *(float4*)(Z + (r0 + i) * LDT + c0) =
                make_float4(ac[i][0], ac[i][1], ac[i][2], ac[i][3]);
        #pragma unroll
        for (int j = 0; j < 4; j++)
            *(float4*)(ZT + (c0 + j) * LDT + r0) =
                make_float4(ac[0][j], ac[1][j], ac[2][j], ac[3][j]);
        __syncthreads();
    };
    // 50 = 0b110010 -> sq, *T, sq, sq, sq, *T, sq  (result in Zb)
    mm(ZaT, Za, Zb, ZbT);  // T^2
    mm(ZbT, Ts, Za, ZaT);  // T^3
    mm(ZaT, Za, Zb, ZbT);  // T^6
    mm(ZbT, Zb, Za, ZaT);  // T^12
    mm(ZaT, Za, Zb, ZbT);  // T^24
    mm(ZbT, Ts, Za, ZaT);  // T^25
    mm(ZaT, Za, Zb, ZbT);  // T^50 -> Zb

    // write M to global for P2
    float* gM = (float*)(ws + 20480);
    for (int i = t; i < 4096; i += 256)
        gM[i] = Zb[(i >> 6) * LDT + (i & 63)];

    // W2 f16 fragments (4096 elems, 16 per thread)
    #pragma unroll
    for (int e = 0; e < 16; e++) {
        int f = t * 16 + e;
        int tt = f >> 9, l = (f >> 3) & 63, j = f & 7;
        int qq = l >> 4, cc = l & 15;
        int n = 16 * (2 * tt + (j >> 2)) + 4 * qq + (j & 3);
        ws[16384 + f] = f16_bits(W2[n * 16 + cc]);
    }
}

// ---------------------------------------------------------------------------
// P2: W1p = M@W1 -> bf16 GEMM1 B-fragments. 64 blocks x 256 threads.
// ---------------------------------------------------------------------------
__global__ __launch_bounds__(256) void ode_pre2(
        const float* __restrict__ W1, unsigned short* __restrict__ ws) {
    const float* M = (const float*)(ws + 20480);
    const int k = blockIdx.x;
    const int col = threadIdx.x;
    const float* mrow = M + k * 64;
    float acc = 0.0f;
    #pragma unroll 8
    for (int d = 0; d < 64; d++)
        acc = fmaf(mrow[d], W1[d * 256 + col], acc);
    const int ntg = col >> 4, cc = col & 15;
    const int kt = k >> 5, qq = (k >> 3) & 3, jj = k & 7;
    ws[((ntg * 2 + kt) * 64 + qq * 16 + cc) * 8 + jj] = bf16_bits(acc);
}

// ---------------------------------------------------------------------------
// Main (byte-exact R9 structure): out = tanh(x @ W1p + b1) @ W2 + b2.
// One-shot, grid = B/256, 512 thr (8 waves), 32 rows/wave. GEMM1 bf16 swapped
// (h in registers), bias via MFMA C-init from LDS, tanh packed-f16 Pade,
// GEMM2 f16 W2-as-A -> transposed C -> coalesced float4 stores. Q-loop
// unroll 1 (R14: unroll 2 regressed). LDS 41984 B, 3 blocks/CU — every
// structural deviation tried (prefetch R8, NITER R11, no-LDS R13, wider
// waves R10, W2-in-regs R16) regressed; compiler targets 64 VGPR here.
// ---------------------------------------------------------------------------
__global__ __launch_bounds__(512, 4) void ode_main(
        const float* __restrict__ x, const unsigned short* __restrict__ wsfrag,
        const float* __restrict__ b1, const float* __restrict__ b2,
        float* __restrict__ out, int B) {
    __shared__ unsigned short w1f[16384];  // bf16 frags, 32KB
    __shared__ unsigned short w2f[4096];   // f16 frags, 8KB
    __shared__ float b1s[256];             // 1KB
    const int t = threadIdx.x;
    const int wid = t >> 6, lane = t & 63;
    const int q = lane >> 4, c = lane & 15;
    const long rowbase = (long)blockIdx.x * 256 + wid * 32;

    // ---- issue x loads first (latency covered by LDS staging)
    float4 xraw[8];
    #pragma unroll
    for (int s = 0; s < 2; s++) {
        long row = rowbase + 16 * s + c;
        if (row >= B) row = B - 1;
        const float* xp = x + row * 64 + q * 8;
        xraw[s * 4 + 0] = *(const float4*)(xp);
        xraw[s * 4 + 1] = *(const float4*)(xp + 4);
        xraw[s * 4 + 2] = *(const float4*)(xp + 32);
        xraw[s * 4 + 3] = *(const float4*)(xp + 36);
    }

    // ---- stage weights
    {
        const uint4* src = (const uint4*)wsfrag;  // 2560 uint4
        uint4* d1 = (uint4*)w1f;
        #pragma unroll
        for (int i = 0; i < 4; i++) d1[t + 512 * i] = src[t + 512 * i];
        ((uint4*)w2f)[t] = src[2048 + t];
        if (t < 64) ((float4*)b1s)[t] = ((const float4*)b1)[t];
    }
    __syncthreads();

    // ---- convert x to bf16 B-fragments, freeing xraw
    bf16x8 xb[2][2];
    #pragma unroll
    for (int s = 0; s < 2; s++)
        #pragma unroll
        for (int kt = 0; kt < 2; kt++) {
            float4 u0 = xraw[s * 4 + kt * 2];
            float4 u1 = xraw[s * 4 + kt * 2 + 1];
            bf16x8 cv;
            cv[0] = (__bf16)u0.x; cv[1] = (__bf16)u0.y;
            cv[2] = (__bf16)u0.z; cv[3] = (__bf16)u0.w;
            cv[4] = (__bf16)u1.x; cv[5] = (__bf16)u1.y;
            cv[6] = (__bf16)u1.z; cv[7] = (__bf16)u1.w;
            xb[s][kt] = cv;
        }

    f32x4 oacc[2] = {{0, 0, 0, 0}, {0, 0, 0, 0}};
    #pragma unroll 1
    for (int Q = 0; Q < 4; Q++) {
        // ---- GEMM1 quarter: 4 ntiles x 2 strips, bias via C-init
        f32x4 acc[2][4];
        #pragma unroll
        for (int m = 0; m < 4; m++) {
            float4 bb = *(const float4*)(b1s + 16 * (4 * Q + m) + 4 * q);
            f32x4 bv = {bb.x, bb.y, bb.z, bb.w};
            acc[0][m] = bv;
            acc[1][m] = bv;
        }
        #pragma unroll
        for (int kt = 0; kt < 2; kt++) {
            #pragma unroll
            for (int m = 0; m < 4; m++) {
                uint4 wraw = *(const uint4*)(w1f + (((4 * Q + m) * 2 + kt) * 64 + lane) * 8);
                bf16x8 wv = __builtin_bit_cast(bf16x8, wraw);
                acc[0][m] = __builtin_amdgcn_mfma_f32_16x16x32_bf16(wv, xb[0][kt], acc[0][m], 0, 0, 0);
                acc[1][m] = __builtin_amdgcn_mfma_f32_16x16x32_bf16(wv, xb[1][kt], acc[1][m], 0, 0, 0);
            }
        }
        // ---- tanh (packed f16) + GEMM2 (2 ttiles), W2 as A-operand ->
        //      transposed output for coalesced stores
        #pragma unroll
        for (int p = 0; p < 2; p++) {
            const int tt = 2 * Q + p;
            uint4 w2r = *(const uint4*)(w2f + (tt * 64 + lane) * 8);
            f16x8 w2v = __builtin_bit_cast(f16x8, w2r);
            #pragma unroll
            for (int s = 0; s < 2; s++) {
                const f32x4 ae = acc[s][2 * p];
                const f32x4 ao = acc[s][2 * p + 1];
                uint4 pr;
                pr.x = tanh2_pk(clamp4(ae[0]), clamp4(ae[1]));
                pr.y = tanh2_pk(clamp4(ae[2]), clamp4(ae[3]));
                pr.z = tanh2_pk(clamp4(ao[0]), clamp4(ao[1]));
                pr.w = tanh2_pk(clamp4(ao[2]), clamp4(ao[3]));
                f16x8 pa = __builtin_bit_cast(f16x8, pr);
                oacc[s] = __builtin_amdgcn_mfma_f32_16x16x32_f16(w2v, pa, oacc[s], 0, 0, 0);
            }
        }
    }
    // ---- store: lane (q,c) holds out[rowbase+16s+c][4q..4q+3] -> float4
    const float4 b2v4 = *(const float4*)(b2 + 4 * q);
    #pragma unroll
    for (int s = 0; s < 2; s++) {
        long row = rowbase + 16 * s + c;
        if (row < B)
            *(float4*)(out + row * 16 + 4 * q) =
                make_float4(oacc[s][0] + b2v4.x, oacc[s][1] + b2v4.y,
                            oacc[s][2] + b2v4.z, oacc[s][3] + b2v4.w);
    }
}

extern "C" void kernel_launch(void* const* d_in, const int* in_sizes, int n_in,
                              void* d_out, int out_size, void* d_ws, size_t ws_size,
                              hipStream_t stream) {
    const float* x  = (const float*)d_in[0];
    const float* A  = (const float*)d_in[1];
    const float* W1 = (const float*)d_in[2];
    const float* b1 = (const float*)d_in[3];
    const float* W2 = (const float*)d_in[4];
    const float* b2 = (const float*)d_in[5];
    float* out = (float*)d_out;
    unsigned short* ws = (unsigned short*)d_ws;  // 40KB frags + 16KB M

    const int B = in_sizes[0] / 64;

    ode_pre1<<<1, 256, 0, stream>>>(A, W2, ws);
    ode_pre2<<<64, 256, 0, stream>>>(W1, ws);
    const int grid = (B + 255) / 256;
    ode_main<<<grid, 512, 0, stream>>>(x, ws, b1, b2, out, B);
}